// Round 10
// baseline (290.894 us; speedup 1.0000x reference)
//
#include <hip/hip_runtime.h>
#include <math.h>

typedef unsigned short u16;
typedef unsigned int u32;
typedef __attribute__((ext_vector_type(8))) _Float16 half8;
typedef __attribute__((ext_vector_type(4))) _Float16 half4;
typedef __attribute__((ext_vector_type(4))) float f32x4;

#define BL 8192          // B*L
#define DD 512           // d_model
#define NN 16            // state size
#define NCHUNK 64        // chunks per sequence
#define SCH 32           // chunk length (NCHUNK*SCH = L = 2048)
#define ZLD 640          // padded width of Z = [Bm(16)|Cm(16)|dt(512)|pad(96)]

#define AS1(p) (const __attribute__((address_space(1))) void*)(p)
#define AS3(p) (__attribute__((address_space(3))) void*)(p)

__device__ __forceinline__ float softplus_f(float z) {
  float w = __builtin_amdgcn_exp2f(-1.4426950408889634f * fabsf(z));
  return fmaxf(z, 0.0f) + 0.69314718055994531f * __builtin_amdgcn_logf(1.0f + w);
}

__device__ __forceinline__ float gelu_erf(float y) {
  // exact-erf gelu via Abramowitz-Stegun 7.1.26 (max err ~1.5e-7)
  float ax = fabsf(y) * 0.70710678118654752f;
  float t  = __builtin_amdgcn_rcpf(1.0f + 0.3275911f * ax);
  float e  = __builtin_amdgcn_exp2f(-1.4426950408889634f * ax * ax);
  float p  = ((((1.061405429f * t - 1.453152027f) * t + 1.421413741f) * t
               - 0.284496736f) * t + 0.254829592f) * t;
  float er = copysignf(1.0f - p * e, y);
  return 0.5f * y * (1.0f + er);
}

// ---------------------------------------------------------------------------
// prep: fp16 copies of x and (transposed) weights, bias concat, A2
// ---------------------------------------------------------------------------
#define PREP_TOT (4194304 + 655360 + 524288 + 262144 + 1280 + 16384)
__global__ __launch_bounds__(256) void prep_kernel(
    const float* __restrict__ x, const float* __restrict__ A_log,
    const float* __restrict__ W_B, const float* __restrict__ b_B,
    const float* __restrict__ W_C, const float* __restrict__ b_C,
    const float* __restrict__ W_dt, const float* __restrict__ b_dt,
    const float* __restrict__ W_mix, const float* __restrict__ W_dec,
    _Float16* __restrict__ x16, _Float16* __restrict__ Wc16,
    _Float16* __restrict__ Wm16, _Float16* __restrict__ Wd16,
    float* __restrict__ bcat, float* __restrict__ A2)
{
  int i = blockIdx.x * 256 + threadIdx.x;
  if (i >= PREP_TOT) return;
  if (i < 4194304) { x16[i] = (_Float16)x[i]; return; }
  i -= 4194304;
  if (i < 655360) {                       // WcatT[l][n(640)][k(512)]
    int l = i / 327680, r = i % 327680, n = r >> 9, k = r & 511;
    float v = 0.0f;
    if (n < 16)       v = W_B[l * 8192 + k * 16 + n];
    else if (n < 32)  v = W_C[l * 8192 + k * 16 + (n - 16)];
    else if (n < 544) v = W_dt[l * 262144 + k * 512 + (n - 32)];
    Wc16[i] = (_Float16)v;
    return;
  }
  i -= 655360;
  if (i < 524288) {                       // WmixT[l][n][k]
    int l = i / 262144, r = i % 262144, n = r >> 9, k = r & 511;
    Wm16[i] = (_Float16)W_mix[l * 262144 + k * 512 + n];
    return;
  }
  i -= 524288;
  if (i < 262144) {                       // WdecT[n][k]
    int n = i >> 9, k = i & 511;
    Wd16[i] = (_Float16)W_dec[k * 512 + n];
    return;
  }
  i -= 262144;
  if (i < 1280) {                         // bcat[l][640]
    int l = i / 640, n = i % 640;
    float v = 0.0f;
    if (n < 16)       v = b_B[l * 16 + n];
    else if (n < 32)  v = b_C[l * 16 + (n - 16)];
    else if (n < 544) v = b_dt[l * 512 + (n - 32)];
    bcat[i] = v;
    return;
  }
  i -= 1280;
  // A2[l][d][n] = -exp(A_log)*log2(e)  (so a = exp2(dt*A2))
  A2[i] = -expf(A_log[i]) * 1.4426950408889634f;
}

// ---------------------------------------------------------------------------
// fp16 MFMA GEMM (cat + decoder): C = A * Bt^T + bias. tile 128x64, BK=64,
// XOR-swizzled LDS (conflict-free ds_read_b128), XCD-aware 1D swizzle,
// LDS-transpose epilogue with coalesced dwordx4 stores.
// MODE 0: +bias;  MODE 1: +bias, softplus cols>=32, skip store col>=544
// ---------------------------------------------------------------------------
template <int MODE>
__global__ __launch_bounds__(256) void gemm_f16(
    const _Float16* __restrict__ A, const _Float16* __restrict__ Bt,
    const float* __restrict__ bias, float* __restrict__ Cmat, int ldc)
{
  const int K = 512;
  int bid = blockIdx.x;
  int xcd = bid & 7;
  int rest = bid >> 3;
  int mloc = rest & 7;
  int nb = rest >> 3;
  int m0 = (xcd * 8 + mloc) * 128;
  int n0 = nb * 64;
  __shared__ __align__(16) char smem[36864];
  _Float16* As = (_Float16*)smem;         // [128][64]
  _Float16* Bs = As + 128 * 64;           // [64][64]
  int tid = threadIdx.x;
  int wave = tid >> 6, lane = tid & 63;
  int wm = (wave >> 1) * 64;
  int wn = (wave & 1) * 32;
  int lrow = lane & 15;
  int q4 = lane >> 4;
  f32x4 acc[4][2] = {};

  int srow = tid >> 3;                            // 0..31
  int scol = ((tid & 7) ^ (srow & 7)) * 8;        // XOR swizzle
  size_t gA = (size_t)(m0 + srow) * K + scol;
  size_t gB = (size_t)(n0 + srow) * K + scol;
  unsigned sdst = (unsigned)(wave * 512);

  for (int k0 = 0; k0 < K; k0 += 64) {
#pragma unroll
    for (int j = 0; j < 4; ++j)
      __builtin_amdgcn_global_load_lds(
          AS1(A + gA + (size_t)(j * 32) * K + k0),
          AS3(&As[j * 2048 + sdst]), 16, 0, 0);
#pragma unroll
    for (int j = 0; j < 2; ++j)
      __builtin_amdgcn_global_load_lds(
          AS1(Bt + gB + (size_t)(j * 32) * K + k0),
          AS3(&Bs[j * 2048 + sdst]), 16, 0, 0);
    __syncthreads();
#pragma unroll
    for (int kk = 0; kk < 2; ++kk) {
      half8 af[4], bf[2];
#pragma unroll
      for (int i = 0; i < 4; ++i) {
        int r = wm + i * 16 + lrow;
        int cb = (kk * 4 + q4) ^ (r & 7);
        af[i] = *(const half8*)&As[r * 64 + cb * 8];
      }
#pragma unroll
      for (int t = 0; t < 2; ++t) {
        int r = wn + t * 16 + lrow;
        int cb = (kk * 4 + q4) ^ (r & 7);
        bf[t] = *(const half8*)&Bs[r * 64 + cb * 8];
      }
#pragma unroll
      for (int i = 0; i < 4; ++i)
#pragma unroll
        for (int t = 0; t < 2; ++t)
          acc[i][t] = __builtin_amdgcn_mfma_f32_16x16x32_f16(af[i], bf[t], acc[i][t], 0, 0, 0);
    }
    __syncthreads();
  }

  float* ct = (float*)smem + wave * (64 * 36);
#pragma unroll
  for (int t = 0; t < 2; ++t) {
    int coll = wn + t * 16 + lrow;
    float bv = bias[n0 + coll];
    bool sp = (MODE == 1) && (n0 + coll >= 32);
#pragma unroll
    for (int i = 0; i < 4; ++i) {
#pragma unroll
      for (int r = 0; r < 4; ++r) {
        float v = acc[i][t][r] + bv;
        if (sp) v = softplus_f(v);
        ct[(i * 16 + q4 * 4 + r) * 36 + (t * 16 + lrow)] = v;
      }
    }
  }
  __syncthreads();
  int r8 = lane >> 3, c8 = lane & 7;
  int colv = n0 + wn + c8 * 4;
  bool do_store = !(MODE == 1 && colv >= 544);
#pragma unroll
  for (int pass = 0; pass < 8; ++pass) {
    int rowl = pass * 8 + r8;
    float4 v = *(const float4*)&ct[rowl * 36 + c8 * 4];
    if (do_store)
      *(float4*)&Cmat[(size_t)(m0 + wm + rowl) * ldc + colv] = v;
  }
}

// ---------------------------------------------------------------------------
// fused mix GEMM + bias + LayerNorm + residual -> h16.
// tile 32(M) x 512(N full row), K=512, BK=32; 512 threads = 8 waves, each
// wave owns a 64-col strip (2 row-tiles x 4 col-tiles of 16x16 MFMA).
// LN stats from accumulators: 16-lane shuffle partials -> LDS cross-wave
// reduce -> per-row mu/rstd; o written via per-wave LDS transpose patch
// (two 4-wave rounds to stay < 64 KB LDS), coalesced fp16 stores.
// RES_PACKED: residual source 0 -> fp32 Xf, 1 -> H itself (read-before-write)
// ---------------------------------------------------------------------------
template <int RES_PACKED>
__global__ __launch_bounds__(512) void gemm_mix_ln(
    const _Float16* __restrict__ A, const _Float16* __restrict__ Bt,
    const float* __restrict__ bias, const float* __restrict__ gam,
    const float* __restrict__ bet, const float* __restrict__ Xf,
    _Float16* __restrict__ H)
{
  const int K = 512;
  int m0 = blockIdx.x * 32;
  // staging (A 2KB + B 32KB = 34 KB) unioned with patch area (4 waves x
  // 32x68x4 = 34816 B); stats after: 32x8x2 + 32x2 floats
  __shared__ __align__(16) char smem[34816 + 32 * 8 * 2 * 4 + 32 * 2 * 4];
  _Float16* As = (_Float16*)smem;          // [32][32]
  _Float16* Bs = As + 32 * 32;             // [512][32]
  float* stats = (float*)(smem + 34816);   // [32][8][2]
  float* mv    = stats + 32 * 8 * 2;       // [32][2]
  int tid = threadIdx.x;
  int wave = tid >> 6, lane = tid & 63;
  int lrow = lane & 15, q4 = lane >> 4;
  int wn = wave * 64;
  f32x4 acc[2][4] = {};

  // A staging: 128 chunks, waves 0-1 only. chunk c: row c>>2, slot c&3
  // holds kblock (slot ^ ((row>>1)&3))
  int rA = tid >> 2, sA = tid & 3;
  size_t gA = (size_t)(m0 + rA) * K + ((sA ^ ((rA >> 1) & 3)) * 8);
  // B staging: 2048 chunks, 4 per thread
  size_t gB[4]; unsigned dB[4];
#pragma unroll
  for (int j = 0; j < 4; ++j) {
    int c = j * 512 + tid;
    int r = c >> 2, s = c & 3;
    gB[j] = (size_t)r * K + ((s ^ ((r >> 1) & 3)) * 8);
    dB[j] = c * 8;
  }

  for (int k0 = 0; k0 < K; k0 += 32) {
    if (wave < 2)
      __builtin_amdgcn_global_load_lds(AS1(A + gA + k0), AS3(As + tid * 8), 16, 0, 0);
#pragma unroll
    for (int j = 0; j < 4; ++j)
      __builtin_amdgcn_global_load_lds(AS1(Bt + gB[j] + k0), AS3(Bs + dB[j]), 16, 0, 0);
    __syncthreads();
    half8 af[2], bf[4];
#pragma unroll
    for (int i = 0; i < 2; ++i) {
      int r = i * 16 + lrow;
      af[i] = *(const half8*)&As[r * 32 + ((q4 ^ ((r >> 1) & 3)) * 8)];
    }
#pragma unroll
    for (int t = 0; t < 4; ++t) {
      int n = wn + t * 16 + lrow;
      bf[t] = *(const half8*)&Bs[n * 32 + ((q4 ^ ((n >> 1) & 3)) * 8)];
    }
#pragma unroll
    for (int i = 0; i < 2; ++i)
#pragma unroll
      for (int t = 0; t < 4; ++t)
        acc[i][t] = __builtin_amdgcn_mfma_f32_16x16x32_f16(af[i], bf[t], acc[i][t], 0, 0, 0);
    __syncthreads();
  }

  // per-lane col constants
  float bv[4], gv[4], betv[4];
#pragma unroll
  for (int t = 0; t < 4; ++t) {
    int col = wn + t * 16 + lrow;
    bv[t] = bias[col]; gv[t] = gam[col]; betv[t] = bet[col];
  }

  // ---- LN stats: lane partial over its 4 cols, per (i,rr) row ----
#pragma unroll
  for (int i = 0; i < 2; ++i)
#pragma unroll
    for (int rr = 0; rr < 4; ++rr) {
      float s = 0.0f, sq = 0.0f;
#pragma unroll
      for (int t = 0; t < 4; ++t) {
        float v = acc[i][t][rr] + bv[t];
        s += v; sq += v * v;
      }
#pragma unroll
      for (int off = 8; off; off >>= 1) {
        s += __shfl_xor(s, off, 64);
        sq += __shfl_xor(sq, off, 64);
      }
      if (lrow == 0) {
        int row = i * 16 + q4 * 4 + rr;
        stats[row * 16 + wave * 2 + 0] = s;
        stats[row * 16 + wave * 2 + 1] = sq;
      }
    }
  __syncthreads();
  if (tid < 32) {
    float s = 0.0f, sq = 0.0f;
#pragma unroll
    for (int w = 0; w < 8; ++w) {
      s += stats[tid * 16 + w * 2 + 0];
      sq += stats[tid * 16 + w * 2 + 1];
    }
    float mu = s * (1.0f / 512.0f);
    float var = sq * (1.0f / 512.0f) - mu * mu;
    mv[tid * 2 + 0] = mu;
    mv[tid * 2 + 1] = rsqrtf(var + 1e-5f);
  }
  __syncthreads();

  // ---- two rounds of 4 waves: patch write (LN applied) + readback/store ----
  float* patch = (float*)smem;             // [4 waves][32][68]
#pragma unroll
  for (int half = 0; half < 2; ++half) {
    if ((wave >> 2) == half) {
      float* pw = patch + (wave & 3) * (32 * 68);
#pragma unroll
      for (int i = 0; i < 2; ++i)
#pragma unroll
        for (int rr = 0; rr < 4; ++rr) {
          int row = i * 16 + q4 * 4 + rr;
          float mu = mv[row * 2 + 0], rstd = mv[row * 2 + 1];
#pragma unroll
          for (int t = 0; t < 4; ++t) {
            float v = acc[i][t][rr] + bv[t];
            pw[row * 68 + t * 16 + lrow] = (v - mu) * rstd * gv[t] + betv[t];
          }
        }
    }
    __syncthreads();
    // readback: 2048 float4-units over 512 threads = 4 passes
#pragma unroll
    for (int p = 0; p < 4; ++p) {
      int idx = p * 512 + tid;             // 0..2047
      int row = idx >> 6, c = idx & 63;    // c: 64 float4 units per row
      int w4 = c >> 4, c16 = c & 15;       // wave-in-round, unit
      float4 v = *(const float4*)&patch[w4 * (32 * 68) + row * 68 + c16 * 4];
      size_t g = (size_t)(m0 + row) * DD + (half * 4 + w4) * 64 + c16 * 4;
      float r0, r1, r2, r3;
      if (RES_PACKED) {
        half4 hr = *(const half4*)(H + g);
        r0 = (float)hr[0]; r1 = (float)hr[1]; r2 = (float)hr[2]; r3 = (float)hr[3];
      } else {
        float4 fr = *(const float4*)(Xf + g);
        r0 = fr.x; r1 = fr.y; r2 = fr.z; r3 = fr.w;
      }
      half4 hv;
      hv[0] = (_Float16)(v.x + r0); hv[1] = (_Float16)(v.y + r1);
      hv[2] = (_Float16)(v.z + r2); hv[3] = (_Float16)(v.w + r3);
      *(half4*)(H + g) = hv;
    }
    __syncthreads();
  }
}

// ---------------------------------------------------------------------------
// scan phase 1: per (b, chunk, d) cumulative a-product + local scan (h0=0).
// grid = B*NCHUNK*2 blocks of 256 threads. X: fp16.
// ---------------------------------------------------------------------------
__global__ __launch_bounds__(256) void scan_p1(
    const float* __restrict__ Z, const _Float16* __restrict__ Xh,
    const float* __restrict__ A2,
    float* __restrict__ Ach, float* __restrict__ Uch)
{
  int bid = blockIdx.x;
  int dg = bid & 1, c = (bid >> 1) & (NCHUNK - 1), b = bid >> 7;
  int d = dg * 256 + threadIdx.x;
  int row0 = b * 2048 + c * SCH;
  __shared__ float Bsh[SCH * 16];
  for (int i = threadIdx.x; i < SCH * 16; i += 256)
    Bsh[i] = Z[(size_t)(row0 + (i >> 4)) * ZLD + (i & 15)];
  __syncthreads();
  float a2[16];
  const float4* a2v = (const float4*)(A2 + d * 16);
#pragma unroll
  for (int q = 0; q < 4; ++q) {
    float4 f = a2v[q];
    a2[q * 4 + 0] = f.x; a2[q * 4 + 1] = f.y; a2[q * 4 + 2] = f.z; a2[q * 4 + 3] = f.w;
  }
  float ap[16], u[16];
#pragma unroll
  for (int n = 0; n < 16; ++n) { ap[n] = 1.0f; u[n] = 0.0f; }
  for (int t = 0; t < SCH; ++t) {
    size_t row = row0 + t;
    float dtv = Z[row * ZLD + 32 + d];
    float xv = (float)Xh[row * DD + d];
    float dx = dtv * xv;
#pragma unroll
    for (int n = 0; n < 16; ++n) {
      float e = __builtin_amdgcn_exp2f(dtv * a2[n]);
      u[n] = e * u[n] + dx * Bsh[t * 16 + n];
      ap[n] *= e;
    }
  }
  size_t out = ((size_t)(b * NCHUNK + c) * DD + d) * 16;
#pragma unroll
  for (int n = 0; n < 16; ++n) { Ach[out + n] = ap[n]; Uch[out + n] = u[n]; }
}

// ---------------------------------------------------------------------------
// scan phase 2 (segmented): 4 threads per (b,dn), each scans 16 chunks in
// registers; LDS carry exchange; rewrite Uch as Hinit. 512 blocks x 256.
// ---------------------------------------------------------------------------
__global__ __launch_bounds__(256) void scan_p2(
    const float* __restrict__ Ach, float* __restrict__ Uch)
{
  int blk = blockIdx.x;
  int b = blk >> 7;
  int dn = (blk & 127) * 64 + (threadIdx.x & 63);
  int seg = threadIdx.x >> 6;
  size_t base = (size_t)b * NCHUNK * 8192 + dn;
  float a_r[16], u_r[16];
#pragma unroll
  for (int i = 0; i < 16; ++i) {
    size_t idx = base + (size_t)(seg * 16 + i) * 8192;
    a_r[i] = Ach[idx];
    u_r[i] = Uch[idx];
  }
  float Ap = 1.0f, hA = 0.0f;
#pragma unroll
  for (int i = 0; i < 16; ++i) { hA = a_r[i] * hA + u_r[i]; Ap *= a_r[i]; }
  __shared__ float AsegL[4][64], UsegL[4][64];
  AsegL[seg][threadIdx.x & 63] = Ap;
  UsegL[seg][threadIdx.x & 63] = hA;
  __syncthreads();
  float h = 0.0f;
  for (int s = 0; s < seg; ++s)
    h = AsegL[s][threadIdx.x & 63] * h + UsegL[s][threadIdx.x & 63];
#pragma unroll
  for (int i = 0; i < 16; ++i) {
    size_t idx = base + (size_t)(seg * 16 + i) * 8192;
    Uch[idx] = h;
    h = a_r[i] * h + u_r[i];
  }
}

// ---------------------------------------------------------------------------
// scan phase 3: replay chunk with true initial state; y = C.h + Dskip*x;
// gelu(exact erf); write fp16
// ---------------------------------------------------------------------------
__global__ __launch_bounds__(256) void scan_p3(
    const float* __restrict__ Z, const _Float16* __restrict__ Xh,
    const float* __restrict__ A2, const float* __restrict__ Hinit,
    const float* __restrict__ Dskip, _Float16* __restrict__ Yout)
{
  int bid = blockIdx.x;
  int dg = bid & 1, c = (bid >> 1) & (NCHUNK - 1), b = bid >> 7;
  int d = dg * 256 + threadIdx.x;
  int row0 = b * 2048 + c * SCH;
  __shared__ float Bsh[SCH * 16];
  __shared__ float Csh[SCH * 16];
  for (int i = threadIdx.x; i < SCH * 16; i += 256) {
    size_t rz = (size_t)(row0 + (i >> 4)) * ZLD;
    Bsh[i] = Z[rz + (i & 15)];
    Csh[i] = Z[rz + 16 + (i & 15)];
  }
  __syncthreads();
  float a2[16];
  const float4* a2v = (const float4*)(A2 + d * 16);
#pragma unroll
  for (int q = 0; q < 4; ++q) {
    float4 f = a2v[q];
    a2[q * 4 + 0] = f.x; a2[q * 4 + 1] = f.y; a2[q * 4 + 2] = f.z; a2[q * 4 + 3] = f.w;
  }
  float h[16];
  size_t hidx = ((size_t)(b * NCHUNK + c) * DD + d) * 16;
#pragma unroll
  for (int n = 0; n < 16; ++n) h[n] = Hinit[hidx + n];
  float dsk = Dskip[d];
  for (int t = 0; t < SCH; ++t) {
    size_t row = row0 + t;
    float dtv = Z[row * ZLD + 32 + d];
    float xv = (float)Xh[row * DD + d];
    float dx = dtv * xv;
    float acc = 0.0f;
#pragma unroll
    for (int n = 0; n < 16; ++n) {
      float e = __builtin_amdgcn_exp2f(dtv * a2[n]);
      h[n] = e * h[n] + dx * Bsh[t * 16 + n];
      acc += Csh[t * 16 + n] * h[n];
    }
    float y = acc + dsk * xv;
    Yout[row * DD + d] = (_Float16)gelu_erf(y);
  }
}

// ---------------------------------------------------------------------------
extern "C" void kernel_launch(void* const* d_in, const int* in_sizes, int n_in,
                              void* d_out, int out_size, void* d_ws, size_t ws_size,
                              hipStream_t stream) {
  const float* x      = (const float*)d_in[0];
  const float* A_log  = (const float*)d_in[1];
  const float* W_B    = (const float*)d_in[2];
  const float* b_B    = (const float*)d_in[3];
  const float* W_C    = (const float*)d_in[4];
  const float* b_C    = (const float*)d_in[5];
  const float* W_dt   = (const float*)d_in[6];
  const float* b_dt   = (const float*)d_in[7];
  const float* D_skip = (const float*)d_in[8];
  const float* W_mix  = (const float*)d_in[9];
  const float* b_mix  = (const float*)d_in[10];
  const float* ln_g   = (const float*)d_in[11];
  const float* ln_b   = (const float*)d_in[12];
  const float* W_dec  = (const float*)d_in[13];
  const float* b_dec  = (const float*)d_in[14];

  char* ws = (char*)d_ws;
  size_t off = 0;
  _Float16* x16 = (_Float16*)(ws + off);  off += 8388608;  // dedicated
  _Float16* y16 = (_Float16*)(ws + off);  off += 8388608;  // p3 out (fp16)
  _Float16* h16 = (_Float16*)(ws + off);  off += 8388608;  // residual stream
  float* Z    = (float*)(ws + off); off += 20971520;       // [8192][640]
  float* Ach  = (float*)(ws + off); off += 8388608;
  float* Uch  = (float*)(ws + off); off += 8388608;        // partials / Hinit
  _Float16* Wc16 = (_Float16*)(ws + off); off += 1310720;  // [2][640][512]
  _Float16* Wm16 = (_Float16*)(ws + off); off += 1048576;
  _Float16* Wd16 = (_Float16*)(ws + off); off += 524288;
  float* bcat = (float*)(ws + off); off += 5120;           // [2][640]
  float* A2w  = (float*)(ws + off); off += 65536;          // [2][512][16]

  prep_kernel<<<(PREP_TOT + 255) / 256, 256, 0, stream>>>(
      x, A_log, W_B, b_B, W_C, b_C, W_dt, b_dt, W_mix, W_dec,
      x16, Wc16, Wm16, Wd16, bcat, A2w);

  for (int l = 0; l < 2; ++l) {
    const _Float16* Ain = (l == 0) ? x16 : h16;
    gemm_f16<1><<<576, 256, 0, stream>>>(
        Ain, Wc16 + l * 640 * 512, bcat + l * 640, Z, ZLD);
    scan_p1<<<512, 256, 0, stream>>>(Z, Ain, A2w + l * 8192, Ach, Uch);
    scan_p2<<<512, 256, 0, stream>>>(Ach, Uch);
    scan_p3<<<512, 256, 0, stream>>>(Z, Ain, A2w + l * 8192, Uch,
                                     D_skip + l * 512, y16);
    if (l == 0)
      gemm_mix_ln<0><<<256, 512, 0, stream>>>(
          y16, Wm16, b_mix, ln_g, ln_b, x, h16);
    else
      gemm_mix_ln<1><<<256, 512, 0, stream>>>(
          y16, Wm16 + 262144, b_mix + 512, ln_g + 512, ln_b + 512,
          nullptr, h16);
  }
  gemm_f16<0><<<512, 256, 0, stream>>>(
      h16, Wd16, b_dec, (float*)d_out, DD);
}